// Round 14
// baseline (881.715 us; speedup 1.0000x reference)
//
#include <hip/hip_runtime.h>
#include <cmath>
#include <type_traits>

typedef __attribute__((ext_vector_type(8))) short short8;
typedef __attribute__((ext_vector_type(4))) float f32x4;
typedef __attribute__((ext_vector_type(4))) unsigned short us4;
typedef unsigned short u16;

#define BATCH 8192
static constexpr size_t BH = (size_t)BATCH * 256;

__device__ __forceinline__ u16 f2bf(float f) {
    union { float f; unsigned u; } v; v.f = f;
    unsigned r = v.u + 0x7FFFu + ((v.u >> 16) & 1u);
    return (u16)(r >> 16);
}
__device__ __forceinline__ float bf2f(u16 u) {
    union { unsigned u; float f; } v; v.u = ((unsigned)u) << 16;
    return v.f;
}
__device__ __forceinline__ float sigmoidf_(float x) {
    return 1.f / (1.f + __expf(-x));
}
__device__ __forceinline__ short8 cvt8(const float* p) {
    f32x4 lo = *(const f32x4*)p, hi = *(const f32x4*)(p + 4);
    short8 t;
    t[0] = (short)f2bf(lo[0]); t[1] = (short)f2bf(lo[1]);
    t[2] = (short)f2bf(lo[2]); t[3] = (short)f2bf(lo[3]);
    t[4] = (short)f2bf(hi[0]); t[5] = (short)f2bf(hi[1]);
    t[6] = (short)f2bf(hi[2]); t[7] = (short)f2bf(hi[3]);
    return t;
}
__device__ __forceinline__ float dot4(const f32x4& a, const float* b) {
    return a[0] * b[0] + a[1] * b[1] + a[2] * b[2] + a[3] * b[3];
}
template<int N>
__device__ __forceinline__ void vmwait() {
    asm volatile("s_waitcnt vmcnt(%0)" :: "n"(N) : "memory");
    __builtin_amdgcn_sched_barrier(0);
}
__device__ __forceinline__ void lgkm0() {
    asm volatile("s_waitcnt lgkmcnt(0)" ::: "memory");
    __builtin_amdgcn_sched_barrier(0);
}
__device__ __forceinline__ void bar() { __builtin_amdgcn_s_barrier(); }

__device__ __forceinline__ void gl_lds16(const float* g, float* l) {
    __builtin_amdgcn_global_load_lds(
        (const __attribute__((address_space(1))) unsigned int*)(const void*)g,
        (__attribute__((address_space(3))) unsigned int*)(void*)l,
        16, 0, 0);
}

// ---------------- weight conversion ----------------
// dst layout (u16 units, 65536 per chunk):
//  c0: embed_w | c1..4: wtn[l] | c5..8: wsn[l] | c9..12: wt[l][512:768]
//  c13..16: ws[l][0:256] | c17..20: ws[l][512:768] | c21: out_w
__global__ __launch_bounds__(256) void convert_weights(
    const float* __restrict__ embed_w, const float* __restrict__ wtn,
    const float* __restrict__ wsn, const float* __restrict__ wt,
    const float* __restrict__ ws, const float* __restrict__ out_w,
    u16* __restrict__ dst)
{
    int idx = blockIdx.x * 256 + threadIdx.x;
    int e = idx * 4;
    if (e >= 22 * 65536) return;
    int c = e >> 16, o = e & 65535;
    const float* src;
    if (c == 0)      src = embed_w + o;
    else if (c < 5)  src = wtn + (size_t)(c - 1) * 65536 + o;
    else if (c < 9)  src = wsn + (size_t)(c - 5) * 65536 + o;
    else if (c < 13) src = wt + (size_t)(c - 9) * 768 * 256 + 512 * 256 + o;
    else if (c < 17) src = ws + (size_t)(c - 13) * 768 * 256 + o;
    else if (c < 21) src = ws + (size_t)(c - 17) * 768 * 256 + 512 * 256 + o;
    else             src = out_w + o;
    f32x4 v = *(const f32x4*)src;
    us4 r;
#pragma unroll
    for (int j = 0; j < 4; ++j) r[j] = f2bf(v[j]);
    *(us4*)(dst + e) = r;
}

// slab slice map (per row): 0..6 = s_att[J,k=1..7]; 7..14 = t_att[J,k=0..7]; 15..14+J = t_att[jj,7]
template<int J>
__device__ __forceinline__ void stage_row(float* buf,
    const float* __restrict__ t_att, const float* __restrict__ s_att,
    int row0, int r, int lane)
{
    constexpr int NS = (J & 1) ? 18 : 17;
    const size_t ro = (size_t)(row0 + r) * 256 + lane * 4;
    float* base = buf + (size_t)r * NS * 256;
#pragma unroll
    for (int kk = 0; kk < 7; ++kk)
        gl_lds16(s_att + ((size_t)J * 8 + 1 + kk) * BH + ro, base + kk * 256);
#pragma unroll
    for (int kk = 0; kk < 8; ++kk)
        gl_lds16(t_att + ((size_t)J * 8 + kk) * BH + ro, base + (7 + kk) * 256);
#pragma unroll
    for (int jj = 0; jj < J; ++jj)
        gl_lds16(t_att + ((size_t)jj * 8 + 7) * BH + ro, base + (15 + jj) * 256);
}

struct LState {
    float slabA[4][17][256];   // layers 0,2
    float slabB[4][18][256];   // layers 1,3
    u16 snl[4][264];
    u16 tnl[4][264];
    u16 tfl[4][264];
    u16 sfl[4][264];
    u16 scsh[4][4][256];       // slot 0 = S_hist[I] row, 1..I = S_hist[jj]
};

template<int I>
__device__ __forceinline__ void attn_row_lds(const float* cur, int r, int lane, LState& L)
{
    constexpr int NS = (I & 1) ? 18 : 17;
    const float scale = 0.0625f;
    const float* rowp = cur + (size_t)r * NS * 256;

    us4 snu = *(const us4*)&L.snl[r][lane * 4];
    us4 tnu = *(const us4*)&L.tnl[r][lane * 4];
    us4 scu = *(const us4*)&L.scsh[r][0][lane * 4];
    float sn[4], tn[4], Sc[4];
#pragma unroll
    for (int j = 0; j < 4; ++j) { sn[j] = bf2f(snu[j]); tn[j] = bf2f(tnu[j]); Sc[j] = bf2f(scu[j]); }

    constexpr int NV = 9 + I;
    float v[NV];
#pragma unroll
    for (int kk = 0; kk < 7; ++kk)
        v[kk] = dot4(*(const f32x4*)(rowp + kk * 256 + lane * 4), sn);
    v[7] = Sc[0] * sn[0] + Sc[1] * sn[1] + Sc[2] * sn[2] + Sc[3] * sn[3];
#pragma unroll
    for (int jj = 0; jj < I; ++jj)
        v[8 + jj] = dot4(*(const f32x4*)(rowp + (15 + jj) * 256 + lane * 4), tn);
    f32x4 tav7 = *(const f32x4*)(rowp + 14 * 256 + lane * 4);
    v[8 + I] = dot4(tav7, tn);

#pragma unroll
    for (int o = 32; o > 0; o >>= 1)
#pragma unroll
        for (int u = 0; u < NV; ++u) v[u] += __shfl_xor(v[u], o);

    float m = v[0] * scale;
#pragma unroll
    for (int kk = 1; kk < 8; ++kk) m = fmaxf(m, v[kk] * scale);
    float w8[8], den = 0.f;
#pragma unroll
    for (int kk = 0; kk < 8; ++kk) { w8[kk] = __expf(v[kk] * scale - m); den += w8[kk]; }
    float inv = 1.f / den;

    float Tt[4] = {0.f, 0.f, 0.f, 0.f};
#pragma unroll
    for (int kk = 0; kk < 8; ++kk) {
        f32x4 tv = *(const f32x4*)(rowp + (7 + kk) * 256 + lane * 4);
#pragma unroll
        for (int j = 0; j < 4; ++j) Tt[j] += w8[kk] * tv[j];
    }
    us4 ot;
#pragma unroll
    for (int j = 0; j < 4; ++j) {
        float g = sigmoidf_(tn[j]);
        ot[j] = f2bf(tav7[j] * g + (1.f - g) * Tt[j] * inv);
    }
    *(us4*)&L.tfl[r][lane * 4] = ot;

    float ms = fmaxf(0.f, v[8 + I] * scale);
#pragma unroll
    for (int jj = 0; jj < I; ++jj) ms = fmaxf(ms, v[8 + jj] * scale);
    float dens = (float)(7 - I) * __expf(-ms);
    float St[4];
    {
        float w = __expf(v[8 + I] * scale - ms);
        dens += w;
#pragma unroll
        for (int j = 0; j < 4; ++j) St[j] = w * Sc[j];
    }
#pragma unroll
    for (int jj = 0; jj < I; ++jj) {
        float w = __expf(v[8 + jj] * scale - ms);
        dens += w;
        us4 shu = *(const us4*)&L.scsh[r][1 + jj][lane * 4];
#pragma unroll
        for (int j = 0; j < 4; ++j) St[j] += w * bf2f(shu[j]);
    }
    float invs = 1.f / dens;
    us4 os;
#pragma unroll
    for (int j = 0; j < 4; ++j) {
        float g = sigmoidf_(sn[j]);
        os[j] = f2bf(Sc[j] * g + (1.f - g) * St[j] * invs);
    }
    *(us4*)&L.sfl[r][lane * 4] = os;
}

template<int I>
__device__ __forceinline__ void layer_body(
    const float* __restrict__ t_att, const float* __restrict__ s_att,
    u16* __restrict__ S_hist, const u16* __restrict__ Wbf,
    const float* __restrict__ btn, const float* __restrict__ bsn,
    const float* __restrict__ bt, const float* __restrict__ bs,
    LState& L, int lane, int wave, int lr, int kg, int row0, bool prod, int pr, int n0)
{
    constexpr int NS = (I & 1) ? 18 : 17;
    float* cur = (I & 1) ? &L.slabB[0][0][0] : &L.slabA[0][0][0];

    if (!prod) {
        const int cw = wave;
        const size_t ro = (size_t)(row0 + cw) * 256 + lane * 4;
        *(us4*)&L.scsh[cw][0][lane * 4] = *(const us4*)(S_hist + (size_t)I * BH + ro);
#pragma unroll
        for (int jj = 0; jj < I; ++jj)
            *(us4*)&L.scsh[cw][1 + jj][lane * 4] = *(const us4*)(S_hist + (size_t)jj * BH + ro);

        const u16* Wsn = Wbf + (size_t)(5 + I) * 65536;
        const u16* Wtn = Wbf + (size_t)(1 + I) * 65536;
        const u16* Arow = S_hist + (size_t)I * BH + (size_t)(row0 + (lr < 4 ? lr : 0)) * 256;
        const float* Trow = cur + (size_t)(lr < 4 ? lr : 0) * NS * 256 + 14 * 256;
        f32x4 accS[4] = {}, accT[4] = {};
        for (int k0 = 0; k0 < 256; k0 += 32) {
            int k = k0 + kg * 8;
            short8 aS = *(const short8*)(Arow + k);
            short8 aT = cvt8(Trow + k);
#pragma unroll
            for (int nf = 0; nf < 4; ++nf) {
                size_t wo = (size_t)(n0 + nf * 16 + lr) * 256 + k;
                accS[nf] = __builtin_amdgcn_mfma_f32_16x16x32_bf16(aS, *(const short8*)(Wsn + wo), accS[nf], 0, 0, 0);
                accT[nf] = __builtin_amdgcn_mfma_f32_16x16x32_bf16(aT, *(const short8*)(Wtn + wo), accT[nf], 0, 0, 0);
            }
        }
        if (kg == 0) {
#pragma unroll
            for (int nf = 0; nf < 4; ++nf) {
                int n = n0 + nf * 16 + lr;
                float bS = bsn[I * 256 + n], bT = btn[I * 256 + n];
#pragma unroll
                for (int r = 0; r < 4; ++r) {
                    L.snl[r][n] = f2bf(accS[nf][r] + bS);
                    L.tnl[r][n] = f2bf(accT[nf][r] + bT);
                }
            }
        }
        lgkm0();
    }
    bar();  // #2

    if (prod) {
        attn_row_lds<I>(cur, pr, lane, L);
        lgkm0();
        if constexpr (I + 2 <= 3)
            stage_row<I + 2>(cur, t_att, s_att, row0, pr, lane);
    }
    bar();  // #3

    if (!prod) {
        const u16* Wt3 = Wbf + (size_t)(9 + I) * 65536;
        const u16* Ws1 = Wbf + (size_t)(13 + I) * 65536;
        const u16* Ws3 = Wbf + (size_t)(17 + I) * 65536;
        const int ar = (lr < 4 ? lr : 0);
        f32x4 aT[4] = {}, aG[4] = {}, aS[4] = {};
        for (int k0 = 0; k0 < 256; k0 += 32) {
            int k = k0 + kg * 8;
            short8 at = *(const short8*)(&L.tfl[ar][k]);
            short8 as = *(const short8*)(&L.sfl[ar][k]);
#pragma unroll
            for (int nf = 0; nf < 4; ++nf) {
                size_t wo = (size_t)(n0 + nf * 16 + lr) * 256 + k;
                aT[nf] = __builtin_amdgcn_mfma_f32_16x16x32_bf16(at, *(const short8*)(Wt3 + wo), aT[nf], 0, 0, 0);
                aG[nf] = __builtin_amdgcn_mfma_f32_16x16x32_bf16(as, *(const short8*)(Ws1 + wo), aG[nf], 0, 0, 0);
                aS[nf] = __builtin_amdgcn_mfma_f32_16x16x32_bf16(as, *(const short8*)(Ws3 + wo), aS[nf], 0, 0, 0);
            }
        }
        if (kg == 0) {
            const float* b1 = bt + I * 768 + 512;
            const float* b2 = bs + I * 768;
            const float* b3 = bs + I * 768 + 512;
#pragma unroll
            for (int nf = 0; nf < 4; ++nf) {
                int n = n0 + nf * 16 + lr;
                float bb1 = b1[n], bb2 = b2[n], bb3 = b3[n];
#pragma unroll
                for (int r = 0; r < 4; ++r) {
                    float gv = sigmoidf_(aG[nf][r] + bb2);
                    float vv = gv * (aS[nf][r] + bb3) + (1.f - gv) * (aT[nf][r] + bb1);
                    S_hist[(size_t)(I + 1) * BH + (size_t)(row0 + r) * 256 + n] = f2bf(vv);
                }
            }
        }
        vmwait<0>();
    } else {
        if constexpr (I == 0) vmwait<17>();
        else if constexpr (I == 1) vmwait<18>();
        else if constexpr (I == 2) vmwait<0>();
    }
    bar();  // entry of next layer / exit
}

__global__ __launch_bounds__(512, 2) void stau_mega(
    const float* __restrict__ x,
    const float* __restrict__ t_att, const float* __restrict__ s_att,
    u16* __restrict__ S_hist, const u16* __restrict__ Wbf,
    const float* __restrict__ embed_b,
    const float* __restrict__ btn, const float* __restrict__ bsn,
    const float* __restrict__ bt, const float* __restrict__ bs,
    const float* __restrict__ out_b,
    float* __restrict__ outp)
{
    __shared__ __align__(16) LState L;

    const int lane = threadIdx.x & 63;
    const int wave = threadIdx.x >> 6;
    const int lr = lane & 15;
    const int kg = lane >> 4;
    const int row0 = blockIdx.x * 4;
    const bool prod = wave >= 4;
    const int pr = wave - 4;
    const int n0 = (wave & 3) * 64;

    if (prod) {
        stage_row<0>(&L.slabA[0][0][0], t_att, s_att, row0, pr, lane);
        stage_row<1>(&L.slabB[0][0][0], t_att, s_att, row0, pr, lane);
        vmwait<16>();
    } else {
        const float* Ax = x + (size_t)(row0 + (lr < 4 ? lr : 0)) * 256;
        f32x4 acc[4] = {};
        for (int k0 = 0; k0 < 256; k0 += 32) {
            int k = k0 + kg * 8;
            short8 a = cvt8(Ax + k);
#pragma unroll
            for (int nf = 0; nf < 4; ++nf) {
                short8 b = *(const short8*)(Wbf + (size_t)(n0 + nf * 16 + lr) * 256 + k);
                acc[nf] = __builtin_amdgcn_mfma_f32_16x16x32_bf16(a, b, acc[nf], 0, 0, 0);
            }
        }
        if (kg == 0) {
#pragma unroll
            for (int nf = 0; nf < 4; ++nf) {
                int n = n0 + nf * 16 + lr;
                float bn = embed_b[n];
#pragma unroll
                for (int r = 0; r < 4; ++r)
                    S_hist[(size_t)(row0 + r) * 256 + n] = f2bf(acc[nf][r] + bn);
            }
        }
        vmwait<0>();
    }
    bar();

    layer_body<0>(t_att, s_att, S_hist, Wbf, btn, bsn, bt, bs, L, lane, wave, lr, kg, row0, prod, pr, n0);
    layer_body<1>(t_att, s_att, S_hist, Wbf, btn, bsn, bt, bs, L, lane, wave, lr, kg, row0, prod, pr, n0);
    layer_body<2>(t_att, s_att, S_hist, Wbf, btn, bsn, bt, bs, L, lane, wave, lr, kg, row0, prod, pr, n0);
    layer_body<3>(t_att, s_att, S_hist, Wbf, btn, bsn, bt, bs, L, lane, wave, lr, kg, row0, prod, pr, n0);

    if (!prod) {
        const u16* Wo = Wbf + (size_t)21 * 65536;
        const u16* A4 = S_hist + (size_t)4 * BH + (size_t)(row0 + (lr < 4 ? lr : 0)) * 256;
        f32x4 acc[4] = {};
        for (int k0 = 0; k0 < 256; k0 += 32) {
            int k = k0 + kg * 8;
            short8 a = *(const short8*)(A4 + k);
#pragma unroll
            for (int nf = 0; nf < 4; ++nf) {
                short8 b = *(const short8*)(Wo + (size_t)(n0 + nf * 16 + lr) * 256 + k);
                acc[nf] = __builtin_amdgcn_mfma_f32_16x16x32_bf16(a, b, acc[nf], 0, 0, 0);
            }
        }
        if (kg == 0) {
#pragma unroll
            for (int nf = 0; nf < 4; ++nf) {
                int n = n0 + nf * 16 + lr;
                float bn = out_b[n];
#pragma unroll
                for (int r = 0; r < 4; ++r)
                    outp[(size_t)(row0 + r) * 256 + n] = tanhf(acc[nf][r] + bn);
            }
        }
    }
}

extern "C" void kernel_launch(void* const* d_in, const int* in_sizes, int n_in,
                              void* d_out, int out_size, void* d_ws, size_t ws_size,
                              hipStream_t stream)
{
    (void)in_sizes; (void)n_in; (void)out_size; (void)ws_size;
    const float* x       = (const float*)d_in[0];
    const float* t_att   = (const float*)d_in[1];
    const float* s_att   = (const float*)d_in[2];
    const float* embed_w = (const float*)d_in[3];
    const float* embed_b = (const float*)d_in[4];
    const float* wtn     = (const float*)d_in[5];
    const float* btn     = (const float*)d_in[6];
    const float* wsn     = (const float*)d_in[7];
    const float* bsn     = (const float*)d_in[8];
    const float* wt      = (const float*)d_in[9];
    const float* bt      = (const float*)d_in[10];
    const float* ws_in   = (const float*)d_in[11];
    const float* bs      = (const float*)d_in[12];
    const float* out_w   = (const float*)d_in[13];
    const float* out_b   = (const float*)d_in[14];

    u16* wsp    = (u16*)d_ws;
    u16* Wbf    = wsp;                       // 22 * 65536 u16 = 2.88 MB
    u16* S_hist = wsp + (size_t)22 * 65536;  // 5 * BH u16 = 20 MB

    convert_weights<<<1408, 256, 0, stream>>>(embed_w, wtn, wsn, wt, ws_in, out_w, Wbf);

    stau_mega<<<BATCH / 4, 512, 0, stream>>>(
        x, t_att, s_att, S_hist, Wbf, embed_b, btn, bsn, bt, bs, out_b, (float*)d_out);
}

// Round 15
// 269.005 us; speedup vs baseline: 3.2777x; 3.2777x over previous
//
#include <hip/hip_runtime.h>
#include <cmath>

typedef __attribute__((ext_vector_type(8))) short short8;
typedef __attribute__((ext_vector_type(4))) float f32x4;
typedef __attribute__((ext_vector_type(4))) unsigned short us4;
typedef unsigned short u16;

#define BATCH 8192
static constexpr size_t BH = (size_t)BATCH * 256;
#define LPAD 264  // u16 LDS row stride (528 B)

__device__ __forceinline__ u16 f2bf(float f) {
    union { float f; unsigned u; } v; v.f = f;
    unsigned r = v.u + 0x7FFFu + ((v.u >> 16) & 1u);
    return (u16)(r >> 16);
}
__device__ __forceinline__ float bf2f(u16 u) {
    union { unsigned u; float f; } v; v.u = ((unsigned)u) << 16;
    return v.f;
}
__device__ __forceinline__ float sigmoidf_(float x) {
    return 1.f / (1.f + __expf(-x));
}
__device__ __forceinline__ short8 cvt8(const float* p) {
    f32x4 lo = *(const f32x4*)p, hi = *(const f32x4*)(p + 4);
    short8 t;
    t[0] = (short)f2bf(lo[0]); t[1] = (short)f2bf(lo[1]);
    t[2] = (short)f2bf(lo[2]); t[3] = (short)f2bf(lo[3]);
    t[4] = (short)f2bf(hi[0]); t[5] = (short)f2bf(hi[1]);
    t[6] = (short)f2bf(hi[2]); t[7] = (short)f2bf(hi[3]);
    return t;
}
__device__ __forceinline__ float dot4(const f32x4& a, const float* b) {
    return a[0] * b[0] + a[1] * b[1] + a[2] * b[2] + a[3] * b[3];
}

// ---------------- weight conversion ----------------
// dst layout (u16 units, 65536 per chunk):
//  c0: embed_w | c1..4: wtn[l] | c5..8: wsn[l] | c9..12: wt[l][512:768]
//  c13..16: ws[l][0:256] | c17..20: ws[l][512:768] | c21: out_w
__global__ __launch_bounds__(256) void convert_weights(
    const float* __restrict__ embed_w, const float* __restrict__ wtn,
    const float* __restrict__ wsn, const float* __restrict__ wt,
    const float* __restrict__ ws, const float* __restrict__ out_w,
    u16* __restrict__ dst)
{
    int idx = blockIdx.x * 256 + threadIdx.x;
    int e = idx * 4;
    if (e >= 22 * 65536) return;
    int c = e >> 16, o = e & 65535;
    const float* src;
    if (c == 0)      src = embed_w + o;
    else if (c < 5)  src = wtn + (size_t)(c - 1) * 65536 + o;
    else if (c < 9)  src = wsn + (size_t)(c - 5) * 65536 + o;
    else if (c < 13) src = wt + (size_t)(c - 9) * 768 * 256 + 512 * 256 + o;
    else if (c < 17) src = ws + (size_t)(c - 13) * 768 * 256 + o;
    else if (c < 21) src = ws + (size_t)(c - 17) * 768 * 256 + 512 * 256 + o;
    else             src = out_w + o;
    f32x4 v = *(const f32x4*)src;
    us4 r;
#pragma unroll
    for (int j = 0; j < 4; ++j) r[j] = f2bf(v[j]);
    *(us4*)(dst + e) = r;
}

// ---------------- gemm_one: C[8192,256] = A @ W^T + b ----------------
// block 256 thr (4 waves): M=32 (row0=bx*32), N=128 (col0=by*128); wave w -> 32 cols.
// A staged once in LDS; W streamed from L2 (weights amortized over 32 rows).
template<bool A_F32, int ACT>
__global__ __launch_bounds__(256, 4) void gemm_one(
    const void* __restrict__ Ap, const u16* __restrict__ W,
    const float* __restrict__ bias, void* __restrict__ Cp)
{
    __shared__ __align__(16) u16 A[32][LPAD];
    const int t = threadIdx.x;
    const int row0 = blockIdx.x * 32;
    {
        int r = t >> 3, c0 = (t & 7) * 32;
        if constexpr (A_F32) {
            const float* p = (const float*)Ap + (size_t)(row0 + r) * 256 + c0;
#pragma unroll
            for (int j = 0; j < 4; ++j) *(short8*)&A[r][c0 + j * 8] = cvt8(p + j * 8);
        } else {
            const u16* p = (const u16*)Ap + (size_t)(row0 + r) * 256 + c0;
#pragma unroll
            for (int j = 0; j < 4; ++j) *(short8*)&A[r][c0 + j * 8] = *(const short8*)(p + j * 8);
        }
    }
    __syncthreads();
    const int lane = t & 63, wave = t >> 6;
    const int lr = lane & 15, kg = lane >> 4;
    const int col0 = blockIdx.y * 128 + wave * 32;
    f32x4 acc[2][2] = {};
    for (int k0 = 0; k0 < 256; k0 += 32) {
        int k = k0 + kg * 8;
        short8 a0 = *(const short8*)&A[lr][k];
        short8 a1 = *(const short8*)&A[16 + lr][k];
#pragma unroll
        for (int nt = 0; nt < 2; ++nt) {
            short8 b = *(const short8*)(W + (size_t)(col0 + nt * 16 + lr) * 256 + k);
            acc[0][nt] = __builtin_amdgcn_mfma_f32_16x16x32_bf16(a0, b, acc[0][nt], 0, 0, 0);
            acc[1][nt] = __builtin_amdgcn_mfma_f32_16x16x32_bf16(a1, b, acc[1][nt], 0, 0, 0);
        }
    }
#pragma unroll
    for (int nt = 0; nt < 2; ++nt) {
        int n = col0 + nt * 16 + lr;
        float bn = bias[n];
#pragma unroll
        for (int mt = 0; mt < 2; ++mt) {
            int m0 = row0 + mt * 16 + kg * 4;
#pragma unroll
            for (int r = 0; r < 4; ++r) {
                float v = acc[mt][nt][r] + bn;
                if constexpr (ACT == 0) ((u16*)Cp)[(size_t)(m0 + r) * 256 + n] = f2bf(v);
                else                    ((float*)Cp)[(size_t)(m0 + r) * 256 + n] = tanhf(v);
            }
        }
    }
}

// ---------------- gemm_dual: z=0 -> s_next (bf16 A), z=1 -> t_next (f32 A) ----------------
__global__ __launch_bounds__(256, 4) void gemm_dual(
    const u16* __restrict__ Scur, const float* __restrict__ Tlast,
    const u16* __restrict__ Wsn, const u16* __restrict__ Wtn,
    const float* __restrict__ bsn_l, const float* __restrict__ btn_l,
    u16* __restrict__ sn_g, u16* __restrict__ tn_g)
{
    __shared__ __align__(16) u16 A[32][LPAD];
    const int t = threadIdx.x;
    const int row0 = blockIdx.x * 32;
    const int g = blockIdx.z;
    {
        int r = t >> 3, c0 = (t & 7) * 32;
        if (g) {
            const float* p = Tlast + (size_t)(row0 + r) * 256 + c0;
#pragma unroll
            for (int j = 0; j < 4; ++j) *(short8*)&A[r][c0 + j * 8] = cvt8(p + j * 8);
        } else {
            const u16* p = Scur + (size_t)(row0 + r) * 256 + c0;
#pragma unroll
            for (int j = 0; j < 4; ++j) *(short8*)&A[r][c0 + j * 8] = *(const short8*)(p + j * 8);
        }
    }
    __syncthreads();
    const int lane = t & 63, wave = t >> 6;
    const int lr = lane & 15, kg = lane >> 4;
    const int col0 = blockIdx.y * 128 + wave * 32;
    const u16* W = g ? Wtn : Wsn;
    f32x4 acc[2][2] = {};
    for (int k0 = 0; k0 < 256; k0 += 32) {
        int k = k0 + kg * 8;
        short8 a0 = *(const short8*)&A[lr][k];
        short8 a1 = *(const short8*)&A[16 + lr][k];
#pragma unroll
        for (int nt = 0; nt < 2; ++nt) {
            short8 b = *(const short8*)(W + (size_t)(col0 + nt * 16 + lr) * 256 + k);
            acc[0][nt] = __builtin_amdgcn_mfma_f32_16x16x32_bf16(a0, b, acc[0][nt], 0, 0, 0);
            acc[1][nt] = __builtin_amdgcn_mfma_f32_16x16x32_bf16(a1, b, acc[1][nt], 0, 0, 0);
        }
    }
    const float* bias = g ? btn_l : bsn_l;
    u16* dst = g ? tn_g : sn_g;
#pragma unroll
    for (int nt = 0; nt < 2; ++nt) {
        int n = col0 + nt * 16 + lr;
        float bn = bias[n];
#pragma unroll
        for (int mt = 0; mt < 2; ++mt) {
            int m0 = row0 + mt * 16 + kg * 4;
#pragma unroll
            for (int r = 0; r < 4; ++r)
                dst[(size_t)(m0 + r) * 256 + n] = f2bf(acc[mt][nt][r] + bn);
        }
    }
}

// ---------------- gemm_triple: 3 GEMMs + gated combine -> S_{i+1} ----------------
__global__ __launch_bounds__(256, 2) void gemm_triple(
    const u16* __restrict__ Tf, const u16* __restrict__ Sf,
    const u16* __restrict__ Wt3, const u16* __restrict__ Ws1, const u16* __restrict__ Ws3,
    const float* __restrict__ b1p, const float* __restrict__ b2p, const float* __restrict__ b3p,
    u16* __restrict__ Sout)
{
    __shared__ __align__(16) u16 At[32][LPAD];
    __shared__ __align__(16) u16 As[32][LPAD];
    const int t = threadIdx.x;
    const int row0 = blockIdx.x * 32;
    {
        int r = t >> 3, c0 = (t & 7) * 32;
        size_t off = (size_t)(row0 + r) * 256 + c0;
#pragma unroll
        for (int j = 0; j < 4; ++j) {
            *(short8*)&At[r][c0 + j * 8] = *(const short8*)(Tf + off + j * 8);
            *(short8*)&As[r][c0 + j * 8] = *(const short8*)(Sf + off + j * 8);
        }
    }
    __syncthreads();
    const int lane = t & 63, wave = t >> 6;
    const int lr = lane & 15, kg = lane >> 4;
    const int col0 = blockIdx.y * 128 + wave * 32;
    f32x4 aT[2][2] = {}, aG[2][2] = {}, aS[2][2] = {};
    for (int k0 = 0; k0 < 256; k0 += 32) {
        int k = k0 + kg * 8;
        short8 at0 = *(const short8*)&At[lr][k];
        short8 at1 = *(const short8*)&At[16 + lr][k];
        short8 as0 = *(const short8*)&As[lr][k];
        short8 as1 = *(const short8*)&As[16 + lr][k];
#pragma unroll
        for (int nt = 0; nt < 2; ++nt) {
            size_t wo = (size_t)(col0 + nt * 16 + lr) * 256 + k;
            short8 bT = *(const short8*)(Wt3 + wo);
            short8 bG = *(const short8*)(Ws1 + wo);
            short8 bS = *(const short8*)(Ws3 + wo);
            aT[0][nt] = __builtin_amdgcn_mfma_f32_16x16x32_bf16(at0, bT, aT[0][nt], 0, 0, 0);
            aT[1][nt] = __builtin_amdgcn_mfma_f32_16x16x32_bf16(at1, bT, aT[1][nt], 0, 0, 0);
            aG[0][nt] = __builtin_amdgcn_mfma_f32_16x16x32_bf16(as0, bG, aG[0][nt], 0, 0, 0);
            aG[1][nt] = __builtin_amdgcn_mfma_f32_16x16x32_bf16(as1, bG, aG[1][nt], 0, 0, 0);
            aS[0][nt] = __builtin_amdgcn_mfma_f32_16x16x32_bf16(as0, bS, aS[0][nt], 0, 0, 0);
            aS[1][nt] = __builtin_amdgcn_mfma_f32_16x16x32_bf16(as1, bS, aS[1][nt], 0, 0, 0);
        }
    }
#pragma unroll
    for (int nt = 0; nt < 2; ++nt) {
        int n = col0 + nt * 16 + lr;
        float bb1 = b1p[n], bb2 = b2p[n], bb3 = b3p[n];
#pragma unroll
        for (int mt = 0; mt < 2; ++mt) {
            int m0 = row0 + mt * 16 + kg * 4;
#pragma unroll
            for (int r = 0; r < 4; ++r) {
                float gv = sigmoidf_(aG[mt][nt][r] + bb2);
                float v = gv * (aS[mt][nt][r] + bb3) + (1.f - gv) * (aT[mt][nt][r] + bb1);
                Sout[(size_t)(m0 + r) * 256 + n] = f2bf(v);
            }
        }
    }
}

// ---------------- attention: one wave per row, plain loads, default occupancy ----------------
// grid 2048 x 256 thr (4 rows/block). R1-proven TLP regime (32 waves/CU target) +
// single merged butterfly (one 6-level chain for all 9+I logits).
template<int I>
__global__ __launch_bounds__(256) void attn_k(
    const float* __restrict__ t_att, const float* __restrict__ s_att,
    const u16* __restrict__ S_hist,
    const u16* __restrict__ sn_g, const u16* __restrict__ tn_g,
    u16* __restrict__ tf_g, u16* __restrict__ sf_g)
{
    const int lane = threadIdx.x & 63;
    const int row = blockIdx.x * 4 + (threadIdx.x >> 6);
    const size_t ro = (size_t)row * 256 + lane * 4;
    const float scale = 0.0625f;  // 1/sqrt(256)

    const float* sa = s_att + (size_t)I * 8 * BH + ro;
    const float* ta = t_att + (size_t)I * 8 * BH + ro;

    us4 snu = *(const us4*)(sn_g + ro);
    us4 tnu = *(const us4*)(tn_g + ro);
    us4 scu = *(const us4*)(S_hist + (size_t)I * BH + ro);
    us4 shu[I > 0 ? I : 1];
#pragma unroll
    for (int jj = 0; jj < I; ++jj) shu[jj] = *(const us4*)(S_hist + (size_t)jj * BH + ro);

    f32x4 sav[7], tav[8], tsp[I > 0 ? I : 1];
#pragma unroll
    for (int kk = 0; kk < 7; ++kk) sav[kk] = *(const f32x4*)(sa + (size_t)(kk + 1) * BH);
#pragma unroll
    for (int kk = 0; kk < 8; ++kk) tav[kk] = *(const f32x4*)(ta + (size_t)kk * BH);
#pragma unroll
    for (int jj = 0; jj < I; ++jj) tsp[jj] = *(const f32x4*)(t_att + ((size_t)jj * 8 + 7) * BH + ro);

    float sn[4], tn[4], Sc[4];
#pragma unroll
    for (int j = 0; j < 4; ++j) { sn[j] = bf2f(snu[j]); tn[j] = bf2f(tnu[j]); Sc[j] = bf2f(scu[j]); }

    constexpr int NV = 9 + I;
    float v[NV];
#pragma unroll
    for (int kk = 0; kk < 7; ++kk) v[kk] = dot4(sav[kk], sn);
    v[7] = Sc[0] * sn[0] + Sc[1] * sn[1] + Sc[2] * sn[2] + Sc[3] * sn[3];
#pragma unroll
    for (int jj = 0; jj < I; ++jj) v[8 + jj] = dot4(tsp[jj], tn);
    v[8 + I] = dot4(tav[7], tn);

    // single 6-level butterfly over all NV values
#pragma unroll
    for (int o = 32; o > 0; o >>= 1)
#pragma unroll
        for (int u = 0; u < NV; ++u) v[u] += __shfl_xor(v[u], o);

    // temporal softmax + T_fusion
    float m = v[0] * scale;
#pragma unroll
    for (int kk = 1; kk < 8; ++kk) m = fmaxf(m, v[kk] * scale);
    float w8[8], den = 0.f;
#pragma unroll
    for (int kk = 0; kk < 8; ++kk) { w8[kk] = __expf(v[kk] * scale - m); den += w8[kk]; }
    float inv = 1.f / den;

    float Tt[4] = {0.f, 0.f, 0.f, 0.f};
#pragma unroll
    for (int kk = 0; kk < 8; ++kk)
#pragma unroll
        for (int j = 0; j < 4; ++j) Tt[j] += w8[kk] * tav[kk][j];
    us4 ot;
#pragma unroll
    for (int j = 0; j < 4; ++j) {
        float g = sigmoidf_(tn[j]);
        ot[j] = f2bf(tav[7][j] * g + (1.f - g) * Tt[j] * inv);
    }
    *(us4*)(tf_g + ro) = ot;

    // spatial softmax: keys = [zeros x (7-I), t_att[0,7]..t_att[I,7]]
    float ms = fmaxf(0.f, v[8 + I] * scale);
#pragma unroll
    for (int jj = 0; jj < I; ++jj) ms = fmaxf(ms, v[8 + jj] * scale);
    float dens = (float)(7 - I) * __expf(-ms);
    float St[4];
    {
        float w = __expf(v[8 + I] * scale - ms);
        dens += w;
#pragma unroll
        for (int j = 0; j < 4; ++j) St[j] = w * Sc[j];
    }
#pragma unroll
    for (int jj = 0; jj < I; ++jj) {
        float w = __expf(v[8 + jj] * scale - ms);
        dens += w;
#pragma unroll
        for (int j = 0; j < 4; ++j) St[j] += w * bf2f(shu[jj][j]);
    }
    float invs = 1.f / dens;
    us4 os;
#pragma unroll
    for (int j = 0; j < 4; ++j) {
        float g = sigmoidf_(sn[j]);
        os[j] = f2bf(Sc[j] * g + (1.f - g) * St[j] * invs);
    }
    *(us4*)(sf_g + ro) = os;
}

extern "C" void kernel_launch(void* const* d_in, const int* in_sizes, int n_in,
                              void* d_out, int out_size, void* d_ws, size_t ws_size,
                              hipStream_t stream)
{
    (void)in_sizes; (void)n_in; (void)out_size; (void)ws_size;
    const float* x       = (const float*)d_in[0];
    const float* t_att   = (const float*)d_in[1];
    const float* s_att   = (const float*)d_in[2];
    const float* embed_w = (const float*)d_in[3];
    const float* embed_b = (const float*)d_in[4];
    const float* wtn     = (const float*)d_in[5];
    const float* btn     = (const float*)d_in[6];
    const float* wsn     = (const float*)d_in[7];
    const float* bsn     = (const float*)d_in[8];
    const float* wt      = (const float*)d_in[9];
    const float* bt      = (const float*)d_in[10];
    const float* ws_in   = (const float*)d_in[11];
    const float* bs      = (const float*)d_in[12];
    const float* out_w   = (const float*)d_in[13];
    const float* out_b   = (const float*)d_in[14];

    u16* wsp    = (u16*)d_ws;
    u16* Wbf    = wsp;                       // 22 * 65536 u16
    u16* S_hist = wsp + (size_t)22 * 65536;  // 5 * BH
    u16* sn_g   = S_hist + 5 * BH;
    u16* tn_g   = sn_g + BH;
    u16* tf_g   = tn_g + BH;
    u16* sf_g   = tf_g + BH;

    convert_weights<<<1408, 256, 0, stream>>>(embed_w, wtn, wsn, wt, ws_in, out_w, Wbf);

    dim3 g2(256, 2);

    // S0 = x @ embed_w^T + embed_b
    gemm_one<true, 0><<<g2, 256, 0, stream>>>(x, Wbf, embed_b, S_hist);

    for (int i = 0; i < 4; ++i) {
        gemm_dual<<<dim3(256, 2, 2), 256, 0, stream>>>(
            S_hist + (size_t)i * BH, t_att + ((size_t)i * 8 + 7) * BH,
            Wbf + (size_t)(5 + i) * 65536, Wbf + (size_t)(1 + i) * 65536,
            bsn + i * 256, btn + i * 256, sn_g, tn_g);

        switch (i) {
            case 0: attn_k<0><<<BATCH / 4, 256, 0, stream>>>(t_att, s_att, S_hist, sn_g, tn_g, tf_g, sf_g); break;
            case 1: attn_k<1><<<BATCH / 4, 256, 0, stream>>>(t_att, s_att, S_hist, sn_g, tn_g, tf_g, sf_g); break;
            case 2: attn_k<2><<<BATCH / 4, 256, 0, stream>>>(t_att, s_att, S_hist, sn_g, tn_g, tf_g, sf_g); break;
            case 3: attn_k<3><<<BATCH / 4, 256, 0, stream>>>(t_att, s_att, S_hist, sn_g, tn_g, tf_g, sf_g); break;
        }

        gemm_triple<<<g2, 256, 0, stream>>>(
            tf_g, sf_g,
            Wbf + (size_t)(9 + i) * 65536,
            Wbf + (size_t)(13 + i) * 65536,
            Wbf + (size_t)(17 + i) * 65536,
            bt + i * 768 + 512, bs + i * 768, bs + i * 768 + 512,
            S_hist + (size_t)(i + 1) * BH);
    }

    // out = tanh(S4 @ out_w^T + out_b), f32
    gemm_one<false, 1><<<g2, 256, 0, stream>>>(
        S_hist + (size_t)4 * BH, Wbf + (size_t)21 * 65536, out_b, (float*)d_out);
}